// Round 1
// baseline (2538.236 us; speedup 1.0000x reference)
//
#include <hip/hip_runtime.h>

// ConvM2Cartesian: x[8,32,8,128,128] (*) rotated B-spline kernels -> out[8,32,8,124,124]
// Kernel 1: build ks[o][ci][ko][oct][ky][c8][kx] (4000 floats per (o,ci)) into d_ws.
// Kernel 2: direct conv, fp32 VALU, 8co x 8px register tile per thread,
//           wave-uniform ks reads (SMEM path), LDS-staged x planes.

#define HW_ 128
#define HOUT_ 124
#define LDSROW 132  // pad 128 -> 132 to break stride-128 LDS bank aliasing

__device__ __forceinline__ float b2f(float t) {
  float a = fabsf(t);
  if (a <= 0.5f) return 0.75f - a * a;
  if (a < 1.5f) { float u = 1.5f - a; return 0.5f * u * u; }
  return 0.0f;
}

// One block per (o, ci). basis[tap][node] in LDS, then ks = w . basis.
__global__ __launch_bounds__(256) void build_ks_kernel(
    const float* __restrict__ w, float* __restrict__ ks) {
  __shared__ float basis[125 * 125];
  const int o  = blockIdx.x >> 5;
  const int ci = blockIdx.x & 31;
  const float ang = -(float)o * 0.78539816339744830962f;  // -o * 2pi/8
  const float c0 = cosf(ang), s0 = sinf(ang);
  for (int i = threadIdx.x; i < 125 * 125; i += 256) {
    const int tap = i / 125, node = i - tap * 125;
    const int a  = tap / 25, b  = (tap / 5) % 5, c  = tap % 5;
    const int no = node / 25, ny = (node / 5) % 5, nx = node % 5;
    const float gy = (float)(b - 2), gx = (float)(c - 2);
    const float xr =  gx * c0 + gy * s0;
    const float yr = -gx * s0 + gy * c0;
    basis[i] = b2f((float)(a - no)) * b2f(yr - (float)(ny - 2)) *
               b2f(xr - (float)(nx - 2));
  }
  __syncthreads();
  float* kbase = ks + (size_t)(o * 32 + ci) * 4000;
  for (int i = threadIdx.x; i < 4000; i += 256) {
    const int co = i / 125, tap = i - co * 125;
    const float* wp = w + (size_t)(co * 32 + ci) * 125;
    const float* bp = basis + tap * 125;
    float s = 0.0f;
    #pragma unroll 5
    for (int n = 0; n < 125; ++n) s = fmaf(wp[n], bp[n], s);
    const int ko = tap / 25, ky = (tap / 5) % 5, kx = tap % 5;
    const int oct = co >> 3, cc = co & 7;
    kbase[(((ko * 4 + oct) * 5 + ky) * 8 + cc) * 5 + kx] = s;
  }
}

// One block per (b, o, 4-row strip). 4 waves = 4 co-octs. Thread: 8co x 8px.
__global__ __launch_bounds__(256) void conv_kernel(
    const float* __restrict__ x, const float* __restrict__ ks,
    float* __restrict__ out) {
  __shared__ float plane[8 * LDSROW];
  const int bid = blockIdx.x;
  const int b_  = bid / 248;            // 8 o * 31 strips
  const int rem = bid - b_ * 248;
  const int o   = rem / 31;
  const int y0  = (rem - o * 31) * 4;
  const int t    = threadIdx.x;
  const int lane = t & 63;
  const int oct  = __builtin_amdgcn_readfirstlane(t >> 6);  // wave-uniform co-oct
  const int row_l = lane >> 4;                    // 0..3
  const int seg   = lane & 15;
  const int xseg  = (seg < 15) ? seg * 8 : 116;   // clamp tail (overlap writes identical)

  float acc[8][8];
  #pragma unroll
  for (int c = 0; c < 8; ++c)
    #pragma unroll
    for (int p = 0; p < 8; ++p) acc[c][p] = 0.0f;

  const float* xb = x + (size_t)b_ * (32 * 8 * HW_ * HW_);
  const int stg_r = t >> 5, stg_c = (t & 31) * 4;

  for (int ci = 0; ci < 32; ++ci) {
    const float* kci = ks + (size_t)(o * 32 + ci) * 4000 + oct * 200;
    for (int ko = 0; ko < 5; ++ko) {
      const int j = (o + ko + 6) & 7;  // (o + ko - 2) mod 8 : wrap padding
      const float* src = xb + (size_t)(ci * 8 + j) * (HW_ * HW_) + y0 * HW_;
      __syncthreads();
      {
        const float4 v = *(const float4*)(src + stg_r * HW_ + stg_c);
        *(float4*)&plane[stg_r * LDSROW + stg_c] = v;
      }
      __syncthreads();
      const float* kblk = kci + ko * 800;
      #pragma unroll
      for (int ky = 0; ky < 5; ++ky) {
        float xr[12];
        const float* prow = &plane[(row_l + ky) * LDSROW + xseg];
        *(float4*)&xr[0] = *(const float4*)(prow);
        *(float4*)&xr[4] = *(const float4*)(prow + 4);
        *(float4*)&xr[8] = *(const float4*)(prow + 8);
        const float* kk = kblk + ky * 40;  // wave-uniform -> s_load
        #pragma unroll
        for (int kx = 0; kx < 5; ++kx)
          #pragma unroll
          for (int c = 0; c < 8; ++c) {
            const float kv = kk[c * 5 + kx];
            #pragma unroll
            for (int p = 0; p < 8; ++p)
              acc[c][p] = fmaf(kv, xr[p + kx], acc[c][p]);
          }
      }
    }
  }

  const int y = y0 + row_l;
  #pragma unroll
  for (int c = 0; c < 8; ++c) {
    const int co = oct * 8 + c;
    float* op = out + (size_t)((b_ * 32 + co) * 8 + o) * (HOUT_ * HOUT_) +
                y * HOUT_ + xseg;
    *(float4*)(op)     = make_float4(acc[c][0], acc[c][1], acc[c][2], acc[c][3]);
    *(float4*)(op + 4) = make_float4(acc[c][4], acc[c][5], acc[c][6], acc[c][7]);
  }
}

extern "C" void kernel_launch(void* const* d_in, const int* in_sizes, int n_in,
                              void* d_out, int out_size, void* d_ws, size_t ws_size,
                              hipStream_t stream) {
  const float* x = (const float*)d_in[0];   // [8,32,8,128,128]
  const float* w = (const float*)d_in[1];   // [32,32,125]
  float* out = (float*)d_out;               // [8,32,8,124,124]
  float* ks  = (float*)d_ws;                // 1,024,000 floats (~4 MB)
  hipLaunchKernelGGL(build_ks_kernel, dim3(8 * 32), dim3(256), 0, stream, w, ks);
  hipLaunchKernelGGL(conv_kernel, dim3(8 * 8 * 31), dim3(256), 0, stream, x, ks, out);
}

// Round 5
// 890.429 us; speedup vs baseline: 2.8506x; 2.8506x over previous
//
#include <hip/hip_runtime.h>

// ConvM2Cartesian via implicit GEMM on mfma_f32_16x16x32_f16.
// K = ci (32). A = ks frags (pre-swizzled fp16 in d_ws, global loads, L2-hot).
// B = x tile in LDS, ci-innermost fp16, XOR-swizzled (quad ^= (pixel>>1)&3).
// Wave = 1 output row x 128 px (8 segs) x 32 co (2 cotiles). Block = 8 waves.

typedef _Float16 half8 __attribute__((ext_vector_type(8)));
typedef float f32x4 __attribute__((ext_vector_type(4)));

#define TW 132    // LDS tile width in pixels (124 out + 4 halo + pad)
#define HOUT 124

__device__ __forceinline__ float b2f(float t) {
  float a = fabsf(t);
  if (a <= 0.5f) return 0.75f - a * a;
  if (a < 1.5f) { float u = 1.5f - a; return 0.5f * u * u; }
  return 0.0f;
}

// grid = 200: blk = (o*5 + ko)*5 + ky. Writes ksf frag-layout:
// chunk = ((((o*5+ko)*5+ky)*5+kx)*2+cot), ksf[chunk*512 + lane*8 + j]
//   = ks(co = cot*16 + (lane&15), ci = ((lane>>4)&3)*8 + j) for tap (ko,ky,kx).
__global__ __launch_bounds__(256) void build_ks(const float* __restrict__ w,
                                                _Float16* __restrict__ ksf) {
  __shared__ float basis[5 * 125];
  const int blk = blockIdx.x;
  const int o = blk / 25, ko = (blk / 5) % 5, ky = blk % 5;
  const float ang = -(float)o * 0.78539816339744830962f;  // -o * 2pi/8
  const float c0 = cosf(ang), s0 = sinf(ang);
  for (int i = threadIdx.x; i < 625; i += 256) {
    const int kx = i / 125, node = i - kx * 125;
    const int no = node / 25, ny = (node / 5) % 5, nx = node % 5;
    const float gy = (float)(ky - 2), gx = (float)(kx - 2);
    const float xr = gx * c0 + gy * s0;
    const float yr = -gx * s0 + gy * c0;
    basis[i] = b2f((float)(ko - no)) * b2f(yr - (float)(ny - 2)) *
               b2f(xr - (float)(nx - 2));
  }
  __syncthreads();
  #pragma unroll 1
  for (int p = 0; p < 20; ++p) {
    const int e = threadIdx.x + p * 256;
    const int jj = e & 7, l = (e >> 3) & 63, cot = (e >> 9) & 1, kx = e >> 10;
    const int co = cot * 16 + (l & 15);
    const int ci = ((l >> 4) & 3) * 8 + jj;
    const float* wp = w + (size_t)(co * 32 + ci) * 125;
    const float* bp = basis + kx * 125;
    float s = 0.0f;
    #pragma unroll 5
    for (int n = 0; n < 125; ++n) s = fmaf(wp[n], bp[n], s);
    ksf[((size_t)(blk * 5 + kx) * 2 + cot) * 512 + l * 8 + jj] = (_Float16)s;
  }
}

// grid = 1024: bid = b*128 + o*16 + ystrip. Block: 8 waves, wave wv owns
// out row y0+wv, px 0..127, co 0..31.
__global__ __launch_bounds__(512, 2) void conv_mfma(
    const float* __restrict__ x, const _Float16* __restrict__ ksf,
    float* __restrict__ out) {
  __shared__ __align__(16) char tile[12 * TW * 64];  // 101376 B
  const int bid = blockIdx.x;
  const int b_ = bid >> 7;
  const int rem = bid & 127;
  const int o = rem >> 4;
  const int y0 = (rem & 15) * 8;
  const int t = threadIdx.x;
  const int wv = t >> 6;
  const int l = t & 63;
  const int lg = l >> 4;   // 0..3 : ci-group (k) / D-row group
  const int ln = l & 15;   // A: co ; B: pixel ; D: col

  f32x4 acc[8][2];
  #pragma unroll
  for (int s = 0; s < 8; ++s) {
    acc[s][0] = (f32x4)0.0f;
    acc[s][1] = (f32x4)0.0f;
  }

  const float* xb = x + (size_t)b_ * (32u * 8u * 128u * 128u);

  #pragma unroll 1
  for (int ko = 0; ko < 5; ++ko) {
    const int j = (o + ko + 6) & 7;  // (o + ko - 2) mod 8 : wrap padding
    __syncthreads();
    // ---- stage 12 rows x 128 px x 32 ci : fp32 -> fp16, swizzled ----
    #pragma unroll 1
    for (int task = wv; task < 384; task += 8) {
      const int cb = task & 3;
      const int pb = (task >> 2) & 7;
      const int r = task >> 5;               // 0..11
      const int c2 = cb * 4 + lg;            // ci-pair 0..15
      const int px = pb * 16 + ln;           // 0..127
      int row = y0 + r;
      if (row > 127) row = 127;
      const float* g0 = xb + (size_t)(2 * c2) * (8 * 128 * 128) +
                        (size_t)j * (128 * 128) + row * 128 + px;
      const float f0 = g0[0];
      const float f1 = g0[8 * 128 * 128];
      union { _Float16 h[2]; unsigned u; } cv;
      cv.h[0] = (_Float16)f0;
      cv.h[1] = (_Float16)f1;
      const int pixel = r * TW + px;
      *(unsigned*)(tile + pixel * 64 +
                   (((c2 >> 2) ^ ((pixel >> 1) & 3)) << 4) +
                   ((c2 & 3) << 2)) = cv.u;
    }
    __syncthreads();
    // ---- compute: 25 (ky) x 8 segs x 5 kx x 2 cot ----
    #pragma unroll 1
    for (int ky = 0; ky < 5; ++ky) {
      const _Float16* kbase =
          ksf + (size_t)(((o * 5 + ko) * 5 + ky) * 5) * 1024 + l * 8;
      half8 af[5][2];
      #pragma unroll
      for (int kx = 0; kx < 5; ++kx) {
        af[kx][0] = *(const half8*)(kbase + (size_t)(kx * 2 + 0) * 512);
        af[kx][1] = *(const half8*)(kbase + (size_t)(kx * 2 + 1) * 512);
      }
      const int rbase = (wv + ky) * TW + ln;
      #pragma unroll
      for (int s = 0; s < 8; ++s) {
        #pragma unroll
        for (int kx = 0; kx < 5; ++kx) {
          const int pixel = rbase + s * 16 + kx;
          const half8 bx = *(const half8*)(
              tile + pixel * 64 + ((lg ^ ((pixel >> 1) & 3)) << 4));
          acc[s][0] = __builtin_amdgcn_mfma_f32_16x16x32_f16(af[kx][0], bx,
                                                             acc[s][0], 0, 0, 0);
          acc[s][1] = __builtin_amdgcn_mfma_f32_16x16x32_f16(af[kx][1], bx,
                                                             acc[s][1], 0, 0, 0);
        }
      }
    }
  }

  // ---- store: D col = pixel (ln), row = co (lg*4 + reg) ----
  const int y = y0 + wv;
  if (y < HOUT) {
    #pragma unroll
    for (int s = 0; s < 8; ++s) {
      const int px = s * 16 + ln;
      if (px < HOUT) {
        #pragma unroll
        for (int cot = 0; cot < 2; ++cot) {
          #pragma unroll
          for (int r = 0; r < 4; ++r) {
            const int co = cot * 16 + lg * 4 + r;
            out[(size_t)((b_ * 32 + co) * 8 + o) * (HOUT * HOUT) + y * HOUT +
                px] = acc[s][cot][r];
          }
        }
      }
    }
  }
}

extern "C" void kernel_launch(void* const* d_in, const int* in_sizes, int n_in,
                              void* d_out, int out_size, void* d_ws, size_t ws_size,
                              hipStream_t stream) {
  const float* x = (const float*)d_in[0];   // [8,32,8,128,128]
  const float* w = (const float*)d_in[1];   // [32,32,125]
  float* out = (float*)d_out;               // [8,32,8,124,124]
  _Float16* ksf = (_Float16*)d_ws;          // 2 MB frag-layout kernel stack
  hipLaunchKernelGGL(build_ks, dim3(200), dim3(256), 0, stream, w, ksf);
  hipLaunchKernelGGL(conv_mfma, dim3(1024), dim3(512), 0, stream, x, ksf, out);
}

// Round 7
// 677.273 us; speedup vs baseline: 3.7477x; 1.3147x over previous
//
#include <hip/hip_runtime.h>
#include <stdint.h>

// ConvM2Cartesian, implicit GEMM on mfma_f32_16x16x32_f16.
// Fast path ws layout (bytes):
//   xh  @ 0        : [b8][j8][y128][px128][ci32] fp16, ci-quads XOR-swizzled
//                    by (px>>1)&3 at write time            (67,108,864 B)
//   ksf @ 67108864 : frag-layout kernel stack fp16          (2,048,000 B)
//   wT  @ 69156864 : [n125][pair1024] fp32                    (512,000 B)
//   bas @ 69668864 : [tapblk200][kx5][n125] fp32              (500,000 B)
// conv tail staging may read up to 32 KB past xh end -> lands in ksf (safe).

typedef _Float16 half8 __attribute__((ext_vector_type(8)));
typedef float f32x4 __attribute__((ext_vector_type(4)));

#define HOUT 124
#define KSF_B 67108864ULL
#define WT_B 69156864ULL
#define BAS_B 69668864ULL
#define WS_NEED 70168864ULL

#define AS1(p) ((const __attribute__((address_space(1))) void*)(p))
#define AS3(p) ((__attribute__((address_space(3))) void*)(p))

__device__ __forceinline__ float b2f(float t) {
  float a = fabsf(t);
  if (a <= 0.5f) return 0.75f - a * a;
  if (a < 1.5f) { float u = 1.5f - a; return 0.5f * u * u; }
  return 0.0f;
}

// ---------------- fast path ----------------

// grid 32: block co. wT[n][co*32+ci] = w[co][ci][n] (coalesced column reads later).
__global__ __launch_bounds__(256) void wt_kernel(const float* __restrict__ w,
                                                 float* __restrict__ wT) {
  __shared__ float lw[4000];
  const int co = blockIdx.x;
  for (int i = threadIdx.x; i < 4000; i += 256) lw[i] = w[(size_t)co * 4000 + i];
  __syncthreads();
  for (int i = threadIdx.x; i < 4000; i += 256) {
    const int n = i >> 5, ci = i & 31;
    wT[(size_t)n * 1024 + co * 32 + ci] = lw[ci * 125 + n];
  }
}

// grid 200: tapblk = (o*5+ko)*5+ky. bas[tapblk][kx][node].
__global__ __launch_bounds__(256) void basis_kernel(float* __restrict__ bas) {
  const int blk = blockIdx.x;
  const int o = blk / 25, ko = (blk / 5) % 5, ky = blk % 5;
  const float ang = -(float)o * 0.78539816339744830962f;
  const float c0 = cosf(ang), s0 = sinf(ang);
  for (int i = threadIdx.x; i < 625; i += 256) {
    const int kx = i / 125, node = i - kx * 125;
    const int no = node / 25, ny = (node / 5) % 5, nx = node % 5;
    const float gy = (float)(ky - 2), gx = (float)(kx - 2);
    const float xr = gx * c0 + gy * s0;
    const float yr = -gx * s0 + gy * c0;
    bas[(size_t)blk * 625 + i] = b2f((float)(ko - no)) *
                                 b2f(yr - (float)(ny - 2)) *
                                 b2f(xr - (float)(nx - 2));
  }
}

// grid 400: blk = tapblk*2 + cot. Coalesced wT columns, uniform bas reads.
__global__ __launch_bounds__(256) void build_ks_fast(
    const float* __restrict__ wT, const float* __restrict__ bas,
    _Float16* __restrict__ ksf) {
  const int blk = blockIdx.x;
  const int tapblk = blk >> 1, cot = blk & 1;
  const float* bp = bas + (size_t)tapblk * 625;      // wave-uniform
  const float* w0 = wT + cot * 512 + threadIdx.x;    // lane-consecutive
  float s0_[5] = {0, 0, 0, 0, 0}, s1_[5] = {0, 0, 0, 0, 0};
  #pragma unroll 5
  for (int n = 0; n < 125; ++n) {
    const float a = w0[(size_t)n * 1024];
    const float b = w0[(size_t)n * 1024 + 256];
    #pragma unroll
    for (int kx = 0; kx < 5; ++kx) {
      const float bb = bp[kx * 125 + n];
      s0_[kx] = fmaf(a, bb, s0_[kx]);
      s1_[kx] = fmaf(b, bb, s1_[kx]);
    }
  }
  #pragma unroll
  for (int pi = 0; pi < 2; ++pi) {
    const int pr = threadIdx.x + pi * 256;
    const int co = cot * 16 + (pr >> 5), ci = pr & 31;
    const int l = ((ci >> 3) << 4) | (co & 15), jj = ci & 7;
    const float* sv = pi ? s1_ : s0_;
    #pragma unroll
    for (int kx = 0; kx < 5; ++kx)
      ksf[((size_t)(tapblk * 5 + kx) * 2 + cot) * 512 + l * 8 + jj] =
          (_Float16)sv[kx];
  }
}

// grid 8192: blk = plane*128 + y, plane = b*8 + j. Transpose ci->innermost,
// fp32->fp16, apply ci-quad swizzle keyed by (px>>1)&3.
__global__ __launch_bounds__(256) void xh_kernel(const float* __restrict__ x,
                                                 _Float16* __restrict__ xh) {
  __shared__ float lx[32][128];
  const int blk = blockIdx.x;
  const int plane = blk >> 7, y = blk & 127;
  const int b_ = plane >> 3, j = plane & 7;
  const int t = threadIdx.x;
  const int ci0 = t >> 5, px0 = (t & 31) * 4;
  #pragma unroll
  for (int p = 0; p < 4; ++p) {
    const int ci = p * 8 + ci0;
    const float4 v = *(const float4*)(
        x + ((size_t)((b_ * 32 + ci) * 8 + j) << 14) + (y << 7) + px0);
    *(float4*)&lx[ci][px0] = v;
  }
  __syncthreads();
  const int px = t >> 1, q0 = (t & 1) * 2;
  const int key = (px >> 1) & 3;
  union { _Float16 h[16]; uint4 u[2]; } v;
  #pragma unroll
  for (int qi = 0; qi < 2; ++qi) {
    const int cib = ((q0 + qi) ^ key) * 8;
    #pragma unroll
    for (int r = 0; r < 8; ++r) v.h[qi * 8 + r] = (_Float16)lx[cib + r][px];
  }
  uint4* dst = (uint4*)(xh + ((size_t)plane << 19) + ((size_t)y << 12) +
                        px * 32 + q0 * 8);
  dst[0] = v.u[0];
  dst[1] = v.u[1];
}

// grid 1024 = b8 x o8 x 16 strips; 512 thr = 8 waves; wave = 1 out row.
__global__ __launch_bounds__(512, 2) void conv_fast(
    const _Float16* __restrict__ xh, const _Float16* __restrict__ ksf,
    float* __restrict__ out) {
  __shared__ __align__(16) char tile[12 * 128 * 64 + 256];  // 98,560 B
  const int bid = blockIdx.x;
  const int b_ = bid >> 7;
  const int rem = bid & 127;
  const int o = rem >> 4;
  const int y0 = (rem & 15) * 8;
  const int t = threadIdx.x;
  const int wv = t >> 6;
  const int l = t & 63;
  const int lg = l >> 4;
  const int ln = l & 15;

  f32x4 acc[8][2];
  #pragma unroll
  for (int s = 0; s < 8; ++s) {
    acc[s][0] = (f32x4)0.0f;
    acc[s][1] = (f32x4)0.0f;
  }

  #pragma unroll 1
  for (int ko = 0; ko < 5; ++ko) {
    const int j = (o + ko + 6) & 7;  // (o + ko - 2) mod 8 : wrap padding
    const char* src = (const char*)xh + ((size_t)(b_ * 8 + j) << 20) +
                      ((size_t)y0 << 13);
    __syncthreads();
    #pragma unroll
    for (int i = 0; i < 12; ++i) {
      const int c = wv * 12 + i;  // 96 x 1KB chunks, linear memcpy
      __builtin_amdgcn_global_load_lds(AS1(src + c * 1024 + l * 16),
                                       AS3(tile + c * 1024), 16, 0, 0);
    }
    asm volatile("s_waitcnt vmcnt(0)");
    __syncthreads();
    #pragma unroll
    for (int ky = 0; ky < 5; ++ky) {
      const _Float16* kbase =
          ksf + (size_t)(((o * 5 + ko) * 5 + ky) * 5) * 1024 + l * 8;
      half8 af[5][2];
      #pragma unroll
      for (int kx = 0; kx < 5; ++kx) {
        af[kx][0] = *(const half8*)(kbase + (size_t)(kx * 2 + 0) * 512);
        af[kx][1] = *(const half8*)(kbase + (size_t)(kx * 2 + 1) * 512);
      }
      const int rb = (wv + ky) * 128 + ln;
      #pragma unroll
      for (int s = 0; s < 8; ++s) {
        #pragma unroll
        for (int kx = 0; kx < 5; ++kx) {
          const int pixel = rb + s * 16 + kx;
          const half8 bx = *(const half8*)(
              tile + pixel * 64 + ((lg ^ ((pixel >> 1) & 3)) << 4));
          acc[s][0] = __builtin_amdgcn_mfma_f32_16x16x32_f16(af[kx][0], bx,
                                                             acc[s][0], 0, 0, 0);
          acc[s][1] = __builtin_amdgcn_mfma_f32_16x16x32_f16(af[kx][1], bx,
                                                             acc[s][1], 0, 0, 0);
        }
      }
    }
  }

  const int y = y0 + wv;
  if (y < HOUT) {
    #pragma unroll
    for (int s = 0; s < 8; ++s) {
      const int px = s * 16 + ln;
      if (px < HOUT) {
        #pragma unroll
        for (int cot = 0; cot < 2; ++cot) {
          #pragma unroll
          for (int r = 0; r < 4; ++r) {
            const int co = cot * 16 + lg * 4 + r;
            out[(size_t)((b_ * 32 + co) * 8 + o) * (HOUT * HOUT) + y * HOUT +
                px] = acc[s][cot][r];
          }
        }
      }
    }
  }
}

// ---------------- fallback path (R5, measured-good) ----------------

__global__ __launch_bounds__(256) void build_ks(const float* __restrict__ w,
                                                _Float16* __restrict__ ksf) {
  __shared__ float basis[5 * 125];
  const int blk = blockIdx.x;
  const int o = blk / 25, ko = (blk / 5) % 5, ky = blk % 5;
  const float ang = -(float)o * 0.78539816339744830962f;
  const float c0 = cosf(ang), s0 = sinf(ang);
  for (int i = threadIdx.x; i < 625; i += 256) {
    const int kx = i / 125, node = i - kx * 125;
    const int no = node / 25, ny = (node / 5) % 5, nx = node % 5;
    const float gy = (float)(ky - 2), gx = (float)(kx - 2);
    const float xr = gx * c0 + gy * s0;
    const float yr = -gx * s0 + gy * c0;
    basis[i] = b2f((float)(ko - no)) * b2f(yr - (float)(ny - 2)) *
               b2f(xr - (float)(nx - 2));
  }
  __syncthreads();
  #pragma unroll 1
  for (int p = 0; p < 20; ++p) {
    const int e = threadIdx.x + p * 256;
    const int jj = e & 7, l = (e >> 3) & 63, cot = (e >> 9) & 1, kx = e >> 10;
    const int co = cot * 16 + (l & 15);
    const int ci = ((l >> 4) & 3) * 8 + jj;
    const float* wp = w + (size_t)(co * 32 + ci) * 125;
    const float* bp = basis + kx * 125;
    float s = 0.0f;
    #pragma unroll 5
    for (int n = 0; n < 125; ++n) s = fmaf(wp[n], bp[n], s);
    ksf[((size_t)(blk * 5 + kx) * 2 + cot) * 512 + l * 8 + jj] = (_Float16)s;
  }
}

#define TW 132
__global__ __launch_bounds__(512, 2) void conv_mfma(
    const float* __restrict__ x, const _Float16* __restrict__ ksf,
    float* __restrict__ out) {
  __shared__ __align__(16) char tile[12 * TW * 64];
  const int bid = blockIdx.x;
  const int b_ = bid >> 7;
  const int rem = bid & 127;
  const int o = rem >> 4;
  const int y0 = (rem & 15) * 8;
  const int t = threadIdx.x;
  const int wv = t >> 6;
  const int l = t & 63;
  const int lg = l >> 4;
  const int ln = l & 15;

  f32x4 acc[8][2];
  #pragma unroll
  for (int s = 0; s < 8; ++s) {
    acc[s][0] = (f32x4)0.0f;
    acc[s][1] = (f32x4)0.0f;
  }
  const float* xb = x + (size_t)b_ * (32u * 8u * 128u * 128u);

  #pragma unroll 1
  for (int ko = 0; ko < 5; ++ko) {
    const int j = (o + ko + 6) & 7;
    __syncthreads();
    #pragma unroll 1
    for (int task = wv; task < 384; task += 8) {
      const int cb = task & 3;
      const int pb = (task >> 2) & 7;
      const int r = task >> 5;
      const int c2 = cb * 4 + lg;
      const int px = pb * 16 + ln;
      int row = y0 + r;
      if (row > 127) row = 127;
      const float* g0 = xb + (size_t)(2 * c2) * (8 * 128 * 128) +
                        (size_t)j * (128 * 128) + row * 128 + px;
      const float f0 = g0[0];
      const float f1 = g0[8 * 128 * 128];
      union { _Float16 h[2]; unsigned u; } cv;
      cv.h[0] = (_Float16)f0;
      cv.h[1] = (_Float16)f1;
      const int pixel = r * TW + px;
      *(unsigned*)(tile + pixel * 64 +
                   (((c2 >> 2) ^ ((pixel >> 1) & 3)) << 4) +
                   ((c2 & 3) << 2)) = cv.u;
    }
    __syncthreads();
    #pragma unroll 1
    for (int ky = 0; ky < 5; ++ky) {
      const _Float16* kbase =
          ksf + (size_t)(((o * 5 + ko) * 5 + ky) * 5) * 1024 + l * 8;
      half8 af[5][2];
      #pragma unroll
      for (int kx = 0; kx < 5; ++kx) {
        af[kx][0] = *(const half8*)(kbase + (size_t)(kx * 2 + 0) * 512);
        af[kx][1] = *(const half8*)(kbase + (size_t)(kx * 2 + 1) * 512);
      }
      const int rbase = (wv + ky) * TW + ln;
      #pragma unroll
      for (int s = 0; s < 8; ++s) {
        #pragma unroll
        for (int kx = 0; kx < 5; ++kx) {
          const int pixel = rbase + s * 16 + kx;
          const half8 bx = *(const half8*)(
              tile + pixel * 64 + ((lg ^ ((pixel >> 1) & 3)) << 4));
          acc[s][0] = __builtin_amdgcn_mfma_f32_16x16x32_f16(af[kx][0], bx,
                                                             acc[s][0], 0, 0, 0);
          acc[s][1] = __builtin_amdgcn_mfma_f32_16x16x32_f16(af[kx][1], bx,
                                                             acc[s][1], 0, 0, 0);
        }
      }
    }
  }

  const int y = y0 + wv;
  if (y < HOUT) {
    #pragma unroll
    for (int s = 0; s < 8; ++s) {
      const int px = s * 16 + ln;
      if (px < HOUT) {
        #pragma unroll
        for (int cot = 0; cot < 2; ++cot) {
          #pragma unroll
          for (int r = 0; r < 4; ++r) {
            const int co = cot * 16 + lg * 4 + r;
            out[(size_t)((b_ * 32 + co) * 8 + o) * (HOUT * HOUT) + y * HOUT +
                px] = acc[s][cot][r];
          }
        }
      }
    }
  }
}

extern "C" void kernel_launch(void* const* d_in, const int* in_sizes, int n_in,
                              void* d_out, int out_size, void* d_ws, size_t ws_size,
                              hipStream_t stream) {
  const float* x = (const float*)d_in[0];   // [8,32,8,128,128]
  const float* w = (const float*)d_in[1];   // [32,32,125]
  float* out = (float*)d_out;               // [8,32,8,124,124]
  if (ws_size >= WS_NEED) {
    _Float16* xh = (_Float16*)d_ws;
    _Float16* ksf = (_Float16*)((char*)d_ws + KSF_B);
    float* wT = (float*)((char*)d_ws + WT_B);
    float* bas = (float*)((char*)d_ws + BAS_B);
    hipLaunchKernelGGL(wt_kernel, dim3(32), dim3(256), 0, stream, w, wT);
    hipLaunchKernelGGL(basis_kernel, dim3(200), dim3(256), 0, stream, bas);
    hipLaunchKernelGGL(build_ks_fast, dim3(400), dim3(256), 0, stream, wT, bas, ksf);
    hipLaunchKernelGGL(xh_kernel, dim3(8192), dim3(256), 0, stream, x, xh);
    hipLaunchKernelGGL(conv_fast, dim3(1024), dim3(512), 0, stream, xh, ksf, out);
  } else {
    _Float16* ksf = (_Float16*)d_ws;
    hipLaunchKernelGGL(build_ks, dim3(200), dim3(256), 0, stream, w, ksf);
    hipLaunchKernelGGL(conv_mfma, dim3(1024), dim3(512), 0, stream, x, ksf, out);
  }
}

// Round 11
// 569.600 us; speedup vs baseline: 4.4562x; 1.1890x over previous
//
#include <hip/hip_runtime.h>
#include <stdint.h>

// ConvM2Cartesian, implicit GEMM on mfma_f32_16x16x32_f16.
// Fast path ws layout (bytes):
//   xh  @ 0        : [b8][j8][y128][px128][ci32] fp16, ci-quads XOR-swizzled
//                    by (px>>1)&3 at write time            (67,108,864 B)
//   ksf @ 67108864 : frag-layout kernel stack fp16          (2,048,000 B)
//   wT  @ 69156864 : [n125][pair1024] fp32                    (512,000 B)
//   bas @ 69668864 : [tapblk200][kx5][n125] fp32              (500,000 B)

typedef _Float16 half8 __attribute__((ext_vector_type(8)));
typedef float f32x4 __attribute__((ext_vector_type(4)));

#define HOUT 124
#define KSF_B 67108864ULL
#define WT_B 69156864ULL
#define BAS_B 69668864ULL
#define WS_NEED 70168864ULL

#define AS1(p) ((const __attribute__((address_space(1))) void*)(p))
#define AS3(p) ((__attribute__((address_space(3))) void*)(p))

__device__ __forceinline__ float b2f(float t) {
  float a = fabsf(t);
  if (a <= 0.5f) return 0.75f - a * a;
  if (a < 1.5f) { float u = 1.5f - a; return 0.5f * u * u; }
  return 0.0f;
}

// ---------------- fast path ----------------

// grid 32: block co. wT[n][co*32+ci] = w[co][ci][n].
__global__ __launch_bounds__(256) void wt_kernel(const float* __restrict__ w,
                                                 float* __restrict__ wT) {
  __shared__ float lw[4000];
  const int co = blockIdx.x;
  for (int i = threadIdx.x; i < 4000; i += 256) lw[i] = w[(size_t)co * 4000 + i];
  __syncthreads();
  for (int i = threadIdx.x; i < 4000; i += 256) {
    const int n = i >> 5, ci = i & 31;
    wT[(size_t)n * 1024 + co * 32 + ci] = lw[ci * 125 + n];
  }
}

// grid 200: tapblk = (o*5+ko)*5+ky. bas[tapblk][kx][node].
__global__ __launch_bounds__(256) void basis_kernel(float* __restrict__ bas) {
  const int blk = blockIdx.x;
  const int o = blk / 25, ko = (blk / 5) % 5, ky = blk % 5;
  const float ang = -(float)o * 0.78539816339744830962f;
  const float c0 = cosf(ang), s0 = sinf(ang);
  for (int i = threadIdx.x; i < 625; i += 256) {
    const int kx = i / 125, node = i - kx * 125;
    const int no = node / 25, ny = (node / 5) % 5, nx = node % 5;
    const float gy = (float)(ky - 2), gx = (float)(kx - 2);
    const float xr = gx * c0 + gy * s0;
    const float yr = -gx * s0 + gy * c0;
    bas[(size_t)blk * 625 + i] = b2f((float)(ko - no)) *
                                 b2f(yr - (float)(ny - 2)) *
                                 b2f(xr - (float)(nx - 2));
  }
}

// grid 400: blk = tapblk*2 + cot. Coalesced wT columns, uniform bas reads.
__global__ __launch_bounds__(256) void build_ks_fast(
    const float* __restrict__ wT, const float* __restrict__ bas,
    _Float16* __restrict__ ksf) {
  const int blk = blockIdx.x;
  const int tapblk = blk >> 1, cot = blk & 1;
  const float* bp = bas + (size_t)tapblk * 625;
  const float* w0 = wT + cot * 512 + threadIdx.x;
  float s0_[5] = {0, 0, 0, 0, 0}, s1_[5] = {0, 0, 0, 0, 0};
  #pragma unroll 5
  for (int n = 0; n < 125; ++n) {
    const float a = w0[(size_t)n * 1024];
    const float b = w0[(size_t)n * 1024 + 256];
    #pragma unroll
    for (int kx = 0; kx < 5; ++kx) {
      const float bb = bp[kx * 125 + n];
      s0_[kx] = fmaf(a, bb, s0_[kx]);
      s1_[kx] = fmaf(b, bb, s1_[kx]);
    }
  }
  #pragma unroll
  for (int pi = 0; pi < 2; ++pi) {
    const int pr = threadIdx.x + pi * 256;
    const int co = cot * 16 + (pr >> 5), ci = pr & 31;
    const int l = ((ci >> 3) << 4) | (co & 15), jj = ci & 7;
    const float* sv = pi ? s1_ : s0_;
    #pragma unroll
    for (int kx = 0; kx < 5; ++kx)
      ksf[((size_t)(tapblk * 5 + kx) * 2 + cot) * 512 + l * 8 + jj] =
          (_Float16)sv[kx];
  }
}

// grid 8192: transpose ci->innermost, fp32->fp16, ci-quad swizzle by (px>>1)&3.
__global__ __launch_bounds__(256) void xh_kernel(const float* __restrict__ x,
                                                 _Float16* __restrict__ xh) {
  __shared__ float lx[32][128];
  const int blk = blockIdx.x;
  const int plane = blk >> 7, y = blk & 127;
  const int b_ = plane >> 3, j = plane & 7;
  const int t = threadIdx.x;
  const int ci0 = t >> 5, px0 = (t & 31) * 4;
  #pragma unroll
  for (int p = 0; p < 4; ++p) {
    const int ci = p * 8 + ci0;
    const float4 v = *(const float4*)(
        x + ((size_t)((b_ * 32 + ci) * 8 + j) << 14) + (y << 7) + px0);
    *(float4*)&lx[ci][px0] = v;
  }
  __syncthreads();
  const int px = t >> 1, q0 = (t & 1) * 2;
  const int key = (px >> 1) & 3;
  union { _Float16 h[16]; uint4 u[2]; } v;
  #pragma unroll
  for (int qi = 0; qi < 2; ++qi) {
    const int cib = ((q0 + qi) ^ key) * 8;
    #pragma unroll
    for (int r = 0; r < 8; ++r) v.h[qi * 8 + r] = (_Float16)lx[cib + r][px];
  }
  uint4* dst = (uint4*)(xh + ((size_t)plane << 19) + ((size_t)y << 12) +
                        px * 32 + q0 * 8);
  dst[0] = v.u[0];
  dst[1] = v.u[1];
}

// grid 1984 = b8 x o8 x 31 strips; 512 thr = 8 waves; wave = (row, s-half).
// Double-buffered: stage(ko+1) issued after vmcnt(0)+barrier, hidden under
// compute(ko). One barrier per phase; all waits vmcnt(0) (compiler-proof).
__global__ __launch_bounds__(512, 1) void conv_fast2(
    const _Float16* __restrict__ xh, const _Float16* __restrict__ ksf,
    float* __restrict__ out) {
  __shared__ __align__(16) char tile[2][8 * 128 * 64];  // 2 x 65536 B
  const int bid = blockIdx.x;
  const int b_ = bid / 248;
  const int rem = bid - b_ * 248;
  const int o = rem / 31;
  const int y0 = (rem - o * 31) * 4;
  const int t = threadIdx.x;
  const int wv = t >> 6;
  const int l = t & 63;
  const int lg = l >> 4;   // ci-group (k) / D-row group
  const int ln = l & 15;   // B: pixel ; D: col
  const int row = wv >> 1; // 0..3 : output row within strip
  const int h = wv & 1;    // s-half: segs h*4 .. h*4+3

  f32x4 acc[4][2];
  #pragma unroll
  for (int s = 0; s < 4; ++s) {
    acc[s][0] = (f32x4)0.0f;
    acc[s][1] = (f32x4)0.0f;
  }

  const char* xbase = (const char*)xh + ((size_t)b_ << 23);

  // prologue: stage ko=0 into buf 0  (rows y0..y0+7, 64 KB, 8 chunks/wave)
  {
    const int j0 = (o + 6) & 7;
    const char* src = xbase + ((size_t)j0 << 20) + ((size_t)y0 << 13);
    #pragma unroll
    for (int i = 0; i < 8; ++i) {
      const int c = wv * 8 + i;
      __builtin_amdgcn_global_load_lds(AS1(src + c * 1024 + l * 16),
                                       AS3(tile[0] + c * 1024), 16, 0, 0);
    }
  }

  #pragma unroll 1
  for (int ko = 0; ko < 5; ++ko) {
    asm volatile("s_waitcnt vmcnt(0)" ::: "memory");
    __syncthreads();
    if (ko < 4) {  // prefetch next j-plane strip into the other buffer
      const int jn = (o + ko + 7) & 7;  // (o + (ko+1) - 2) mod 8
      const char* src = xbase + ((size_t)jn << 20) + ((size_t)y0 << 13);
      char* dstb = tile[(ko + 1) & 1];
      #pragma unroll
      for (int i = 0; i < 8; ++i) {
        const int c = wv * 8 + i;
        __builtin_amdgcn_global_load_lds(AS1(src + c * 1024 + l * 16),
                                         AS3(dstb + c * 1024), 16, 0, 0);
      }
    }
    __builtin_amdgcn_sched_barrier(0);  // keep prefetch issue before compute
    const char* tb = tile[ko & 1];
    #pragma unroll
    for (int ky = 0; ky < 5; ++ky) {
      const _Float16* kbase =
          ksf + (size_t)(((o * 5 + ko) * 5 + ky) * 5) * 1024 + l * 8;
      half8 af[5][2];
      #pragma unroll
      for (int kx = 0; kx < 5; ++kx) {
        af[kx][0] = *(const half8*)(kbase + (size_t)(kx * 2 + 0) * 512);
        af[kx][1] = *(const half8*)(kbase + (size_t)(kx * 2 + 1) * 512);
      }
      const int rb = (row + ky) * 128 + ln;
      #pragma unroll
      for (int s = 0; s < 4; ++s) {
        #pragma unroll
        for (int kx = 0; kx < 5; ++kx) {
          const int pixel = rb + (h * 4 + s) * 16 + kx;
          const half8 bx = *(const half8*)(
              tb + pixel * 64 + ((lg ^ ((pixel >> 1) & 3)) << 4));
          acc[s][0] = __builtin_amdgcn_mfma_f32_16x16x32_f16(af[kx][0], bx,
                                                             acc[s][0], 0, 0, 0);
          acc[s][1] = __builtin_amdgcn_mfma_f32_16x16x32_f16(af[kx][1], bx,
                                                             acc[s][1], 0, 0, 0);
        }
      }
    }
  }

  // store: D col = pixel (ln), row = co (lg*4 + reg)
  const int y = y0 + row;
  #pragma unroll
  for (int s = 0; s < 4; ++s) {
    const int px = (h * 4 + s) * 16 + ln;
    if (px < HOUT) {
      #pragma unroll
      for (int cot = 0; cot < 2; ++cot) {
        #pragma unroll
        for (int r = 0; r < 4; ++r) {
          const int co = cot * 16 + lg * 4 + r;
          out[(size_t)((b_ * 32 + co) * 8 + o) * (HOUT * HOUT) + y * HOUT +
              px] = acc[s][cot][r];
        }
      }
    }
  }
}

// ---------------- fallback path (R5, measured-good) ----------------

__global__ __launch_bounds__(256) void build_ks(const float* __restrict__ w,
                                                _Float16* __restrict__ ksf) {
  __shared__ float basis[5 * 125];
  const int blk = blockIdx.x;
  const int o = blk / 25, ko = (blk / 5) % 5, ky = blk % 5;
  const float ang = -(float)o * 0.78539816339744830962f;
  const float c0 = cosf(ang), s0 = sinf(ang);
  for (int i = threadIdx.x; i < 625; i += 256) {
    const int kx = i / 125, node = i - kx * 125;
    const int no = node / 25, ny = (node / 5) % 5, nx = node % 5;
    const float gy = (float)(ky - 2), gx = (float)(kx - 2);
    const float xr = gx * c0 + gy * s0;
    const float yr = -gx * s0 + gy * c0;
    basis[i] = b2f((float)(ko - no)) * b2f(yr - (float)(ny - 2)) *
               b2f(xr - (float)(nx - 2));
  }
  __syncthreads();
  #pragma unroll 1
  for (int p = 0; p < 20; ++p) {
    const int e = threadIdx.x + p * 256;
    const int jj = e & 7, l = (e >> 3) & 63, cot = (e >> 9) & 1, kx = e >> 10;
    const int co = cot * 16 + (l & 15);
    const int ci = ((l >> 4) & 3) * 8 + jj;
    const float* wp = w + (size_t)(co * 32 + ci) * 125;
    const float* bp = basis + kx * 125;
    float s = 0.0f;
    #pragma unroll 5
    for (int n = 0; n < 125; ++n) s = fmaf(wp[n], bp[n], s);
    ksf[((size_t)(blk * 5 + kx) * 2 + cot) * 512 + l * 8 + jj] = (_Float16)s;
  }
}

#define TW 132
__global__ __launch_bounds__(512, 2) void conv_mfma(
    const float* __restrict__ x, const _Float16* __restrict__ ksf,
    float* __restrict__ out) {
  __shared__ __align__(16) char tile[12 * TW * 64];
  const int bid = blockIdx.x;
  const int b_ = bid >> 7;
  const int rem = bid & 127;
  const int o = rem >> 4;
  const int y0 = (rem & 15) * 8;
  const int t = threadIdx.x;
  const int wv = t >> 6;
  const int l = t & 63;
  const int lg = l >> 4;
  const int ln = l & 15;

  f32x4 acc[8][2];
  #pragma unroll
  for (int s = 0; s < 8; ++s) {
    acc[s][0] = (f32x4)0.0f;
    acc[s][1] = (f32x4)0.0f;
  }
  const float* xb = x + (size_t)b_ * (32u * 8u * 128u * 128u);

  #pragma unroll 1
  for (int ko = 0; ko < 5; ++ko) {
    const int j = (o + ko + 6) & 7;
    __syncthreads();
    #pragma unroll 1
    for (int task = wv; task < 384; task += 8) {
      const int cb = task & 3;
      const int pb = (task >> 2) & 7;
      const int r = task >> 5;
      const int c2 = cb * 4 + lg;
      const int px = pb * 16 + ln;
      int row = y0 + r;
      if (row > 127) row = 127;
      const float* g0 = xb + (size_t)(2 * c2) * (8 * 128 * 128) +
                        (size_t)j * (128 * 128) + row * 128 + px;
      const float f0 = g0[0];
      const float f1 = g0[8 * 128 * 128];
      union { _Float16 h[2]; unsigned u; } cv;
      cv.h[0] = (_Float16)f0;
      cv.h[1] = (_Float16)f1;
      const int pixel = r * TW + px;
      *(unsigned*)(tile + pixel * 64 +
                   (((c2 >> 2) ^ ((pixel >> 1) & 3)) << 4) +
                   ((c2 & 3) << 2)) = cv.u;
    }
    __syncthreads();
    #pragma unroll 1
    for (int ky = 0; ky < 5; ++ky) {
      const _Float16* kbase =
          ksf + (size_t)(((o * 5 + ko) * 5 + ky) * 5) * 1024 + l * 8;
      half8 af[5][2];
      #pragma unroll
      for (int kx = 0; kx < 5; ++kx) {
        af[kx][0] = *(const half8*)(kbase + (size_t)(kx * 2 + 0) * 512);
        af[kx][1] = *(const half8*)(kbase + (size_t)(kx * 2 + 1) * 512);
      }
      const int rbase = (wv + ky) * TW + ln;
      #pragma unroll
      for (int s = 0; s < 8; ++s) {
        #pragma unroll
        for (int kx = 0; kx < 5; ++kx) {
          const int pixel = rbase + s * 16 + kx;
          const half8 bx = *(const half8*)(
              tile + pixel * 64 + ((lg ^ ((pixel >> 1) & 3)) << 4));
          acc[s][0] = __builtin_amdgcn_mfma_f32_16x16x32_f16(af[kx][0], bx,
                                                             acc[s][0], 0, 0, 0);
          acc[s][1] = __builtin_amdgcn_mfma_f32_16x16x32_f16(af[kx][1], bx,
                                                             acc[s][1], 0, 0, 0);
        }
      }
    }
  }

  const int y = y0 + wv;
  if (y < HOUT) {
    #pragma unroll
    for (int s = 0; s < 8; ++s) {
      const int px = s * 16 + ln;
      if (px < HOUT) {
        #pragma unroll
        for (int cot = 0; cot < 2; ++cot) {
          #pragma unroll
          for (int r = 0; r < 4; ++r) {
            const int co = cot * 16 + lg * 4 + r;
            out[(size_t)((b_ * 32 + co) * 8 + o) * (HOUT * HOUT) + y * HOUT +
                px] = acc[s][cot][r];
          }
        }
      }
    }
  }
}

extern "C" void kernel_launch(void* const* d_in, const int* in_sizes, int n_in,
                              void* d_out, int out_size, void* d_ws, size_t ws_size,
                              hipStream_t stream) {
  const float* x = (const float*)d_in[0];   // [8,32,8,128,128]
  const float* w = (const float*)d_in[1];   // [32,32,125]
  float* out = (float*)d_out;               // [8,32,8,124,124]
  if (ws_size >= WS_NEED) {
    _Float16* xh = (_Float16*)d_ws;
    _Float16* ksf = (_Float16*)((char*)d_ws + KSF_B);
    float* wT = (float*)((char*)d_ws + WT_B);
    float* bas = (float*)((char*)d_ws + BAS_B);
    hipLaunchKernelGGL(wt_kernel, dim3(32), dim3(256), 0, stream, w, wT);
    hipLaunchKernelGGL(basis_kernel, dim3(200), dim3(256), 0, stream, bas);
    hipLaunchKernelGGL(build_ks_fast, dim3(400), dim3(256), 0, stream, wT, bas, ksf);
    hipLaunchKernelGGL(xh_kernel, dim3(8192), dim3(256), 0, stream, x, xh);
    hipLaunchKernelGGL(conv_fast2, dim3(1984), dim3(512), 0, stream, xh, ksf, out);
  } else {
    _Float16* ksf = (_Float16*)d_ws;
    hipLaunchKernelGGL(build_ks, dim3(200), dim3(256), 0, stream, w, ksf);
    hipLaunchKernelGGL(conv_mfma, dim3(1024), dim3(512), 0, stream, x, ksf, out);
  }
}